// Round 6
// baseline (165.642 us; speedup 1.0000x reference)
//
#include <hip/hip_runtime.h>
#include <stdint.h>

#define HIDDEN 768
#define META 25
#define EDC 300
#define BB 2
#define NMENT 2000
#define NPAIRS 40000
#define M_ROWS (BB * NMENT)       // 4000
#define M_PAD 4096                // 32 * 128
#define N_OUT 1536
#define TOTAL_PAIRS (BB * NPAIRS) // 80000
#define BK 64                     // row = 128 B = full 32-bank span (enables swizzle)

typedef __bf16 bf16x8 __attribute__((ext_vector_type(8)));
typedef float f32x4 __attribute__((ext_vector_type(4)));

static __device__ __forceinline__ float bf2f(unsigned short u) {
    union { unsigned int u; float f; } v; v.u = ((unsigned int)u) << 16; return v.f;
}
static __device__ __forceinline__ float2 bf2x(unsigned int u) {
    union { unsigned int x; float f; } lo, hi;
    lo.x = u << 16; hi.x = u & 0xffff0000u;
    float2 r; r.x = lo.f; r.y = hi.f; return r;
}
static __device__ __forceinline__ unsigned short f2bf(float f) {
    union { float f; unsigned int u; } v; v.f = f;
    unsigned int u = v.u;
    unsigned int r = (u + 0x7FFFu + ((u >> 16) & 1u)) >> 16;   // RNE
    return (unsigned short)r;
}

#define GLOAD_LDS16(g, l)                                                            \
    __builtin_amdgcn_global_load_lds((const __attribute__((address_space(1))) void*)(g), \
                                     (__attribute__((address_space(3))) void*)(l), 16, 0, 0)

// ---- fused prep: convM | convW | ed prep | W2->bf16 ----
#define NB_CONVM 3072              // (4096*768/4)/256
#define NB_CONVW 576               // 24*24
#define NB_PREP  900               // 300*768/256
#define NB_W2    3                 // 768/256

// ATTRIBUTION: internal rep-loop (reps is a RUNTIME arg -> trip count opaque;
// per-rep pointer offset (rep>>20)==0 at runtime but unprovable at compile
// time, so loads can't be hoisted out of the loop). reps=4 makes this a
// single dispatch of ~4x its true duration so it crosses the ~44us fill
// floor and appears in the rocprof top-5 WITH counters. Idempotent: every
// rep writes identical values.
__global__ __launch_bounds__(256) void k_prep_all(
        const float* __restrict__ M, unsigned short* __restrict__ Mb,
        const float* __restrict__ W1, unsigned short* __restrict__ Wt,
        const float* __restrict__ ed_table, const float* __restrict__ b1,
        unsigned short* __restrict__ Epp,
        const float* __restrict__ W2, unsigned short* __restrict__ W2b,
        int reps) {
    const int blk = blockIdx.x;
    const int t = threadIdx.x;
    for (int rep = 0; rep < reps; ++rep) {
        const int z = rep >> 20;                 // 0 at runtime, opaque statically
        const float* Mr  = M + z;
        const float* W1r = W1 + z;
        const float* edr = ed_table + z;
        if (blk < NB_CONVM) {
            int idx = (blk * 256 + t) * 4;
            int row = idx / HIDDEN;
            ushort4 o;
            if (row < M_ROWS) {
                const float4 v = *(const float4*)(Mr + idx);
                o.x = f2bf(v.x); o.y = f2bf(v.y); o.z = f2bf(v.z); o.w = f2bf(v.w);
            } else {
                o.x = 0; o.y = 0; o.z = 0; o.w = 0;
            }
            *(ushort4*)(Mb + idx) = o;
        } else if (blk < NB_CONVM + NB_CONVW) {
            __shared__ float tile[32][68];
            int id = blk - NB_CONVM;
            int nt = id % 24, kt = id / 24;
            int n0 = nt * 64, k0 = kt * 32;
            int tk = t >> 4, tn = (t & 15) * 4;
            int srcRowOff = (n0 < HIDDEN) ? 0 : HIDDEN;
            int srcColBase = (n0 < HIDDEN) ? n0 : (n0 - HIDDEN);
            {
                const float4 v0 = *(const float4*)(W1r + (size_t)(k0 + tk + srcRowOff) * HIDDEN + srcColBase + tn);
                tile[tk][tn] = v0.x; tile[tk][tn + 1] = v0.y; tile[tk][tn + 2] = v0.z; tile[tk][tn + 3] = v0.w;
                const float4 v1 = *(const float4*)(W1r + (size_t)(k0 + tk + 16 + srcRowOff) * HIDDEN + srcColBase + tn);
                tile[tk + 16][tn] = v1.x; tile[tk + 16][tn + 1] = v1.y; tile[tk + 16][tn + 2] = v1.z; tile[tk + 16][tn + 3] = v1.w;
            }
            __syncthreads();
            int wn = t >> 2, wk = (t & 3) * 8;
            unsigned int p0 = (unsigned int)f2bf(tile[wk + 0][wn]) | ((unsigned int)f2bf(tile[wk + 1][wn]) << 16);
            unsigned int p1 = (unsigned int)f2bf(tile[wk + 2][wn]) | ((unsigned int)f2bf(tile[wk + 3][wn]) << 16);
            unsigned int p2 = (unsigned int)f2bf(tile[wk + 4][wn]) | ((unsigned int)f2bf(tile[wk + 5][wn]) << 16);
            unsigned int p3 = (unsigned int)f2bf(tile[wk + 6][wn]) | ((unsigned int)f2bf(tile[wk + 7][wn]) << 16);
            uint4 pk; pk.x = p0; pk.y = p1; pk.z = p2; pk.w = p3;
            *(uint4*)(Wt + (size_t)(n0 + wn) * HIDDEN + k0 + wk) = pk;
            __syncthreads();   // rep boundary: protect tile reuse
        } else if (blk < NB_CONVM + NB_CONVW + NB_PREP) {
            int id = (blk - NB_CONVM - NB_CONVW) * 256 + t;
            int e = id / HIDDEN, n = id - e * HIDDEN;
            float acc = b1[n];
#pragma unroll
            for (int k = 0; k < META; k++)
                acc += edr[e * META + k] * W1r[(size_t)(2 * HIDDEN + k) * HIDDEN + n];
            Epp[id] = f2bf(acc);
        } else {
            int id = (blk - NB_CONVM - NB_CONVW - NB_PREP) * 256 + t;
            if (id < HIDDEN) W2b[id] = f2bf(W2[id + z]);
        }
    }
}

// ---- AW[4096][1536] = Mb @ Wt^T ---- (baseline compute, + attribution rep loop)
__global__ __launch_bounds__(256) void k_gemm(const unsigned short* __restrict__ Mb,
                                              const unsigned short* __restrict__ Wt,
                                              unsigned short* __restrict__ AW,
                                              int reps) {
    __shared__ unsigned short As[128 * BK];   // 16 KB
    __shared__ unsigned short Bs[64 * BK];    // 8 KB
    const int m0 = blockIdx.x * 128;
    const int n0 = blockIdx.y * 64;
    const int t = threadIdx.x, w = t >> 6, lane = t & 63;
    const int wm = (w & 1) * 64, wn = (w >> 1) * 32;
    const int q = lane >> 4, r = lane & 15;
    const int lrow = lane >> 3;
    const int lcol = ((((lane & 7) - lrow) & 7)) * 8;      // shorts
    const unsigned short* gA = Mb + (size_t)(m0 + w * 32 + lrow) * HIDDEN + lcol;
    const unsigned short* gB = Wt + (size_t)(n0 + w * 16 + lrow) * HIDDEN + lcol;
    unsigned short* lA = As + (w * 32) * BK;               // wave-uniform LDS base
    unsigned short* lB = Bs + (w * 16) * BK;
    for (int rep = 0; rep < reps; ++rep) {
        const int z = rep >> 20;               // 0 at runtime, opaque statically
        const unsigned short* gAr = gA + z;
        const unsigned short* gBr = gB + z;
        f32x4 acc[4][2] = {};
        for (int k0 = 0; k0 < HIDDEN; k0 += BK) {
            GLOAD_LDS16(gAr + k0, lA);
            GLOAD_LDS16(gAr + k0 + 8 * HIDDEN,  lA + 8 * BK);
            GLOAD_LDS16(gAr + k0 + 16 * HIDDEN, lA + 16 * BK);
            GLOAD_LDS16(gAr + k0 + 24 * HIDDEN, lA + 24 * BK);
            GLOAD_LDS16(gBr + k0, lB);
            GLOAD_LDS16(gBr + k0 + 8 * HIDDEN,  lB + 8 * BK);
            __syncthreads();
            bf16x8 af[4][2], bfr[2][2];
            const int rs = r & 7;
#pragma unroll
            for (int i = 0; i < 4; i++)
#pragma unroll
                for (int s = 0; s < 2; s++)
                    af[i][s] = *(const bf16x8*)&As[(wm + i * 16 + r) * BK + 8 * ((q + 4 * s + rs) & 7)];
#pragma unroll
            for (int j = 0; j < 2; j++)
#pragma unroll
                for (int s = 0; s < 2; s++)
                    bfr[j][s] = *(const bf16x8*)&Bs[(wn + j * 16 + r) * BK + 8 * ((q + 4 * s + rs) & 7)];
#pragma unroll
            for (int i = 0; i < 4; i++)
#pragma unroll
                for (int j = 0; j < 2; j++) {
                    acc[i][j] = __builtin_amdgcn_mfma_f32_16x16x32_bf16(af[i][0], bfr[j][0], acc[i][j], 0, 0, 0);
                    acc[i][j] = __builtin_amdgcn_mfma_f32_16x16x32_bf16(af[i][1], bfr[j][1], acc[i][j], 0, 0, 0);
                }
            __syncthreads();
        }
        const int colb = n0 + wn + (lane & 15);
        const int rowb = m0 + wm + (lane >> 4) * 4;
#pragma unroll
        for (int i = 0; i < 4; i++)
#pragma unroll
            for (int j = 0; j < 2; j++) {
                unsigned short* dst = AW + (size_t)(rowb + i * 16) * N_OUT + colb + j * 16;
#pragma unroll
                for (int reg = 0; reg < 4; reg++)
                    dst[(size_t)reg * N_OUT] = f2bf(acc[i][j][reg]);
            }
        __syncthreads();   // rep boundary
    }
}

// ---- pair phase: 4 pairs per wave, ALL loads 16 B ---- (baseline, measured 24.5 us)
__global__ __launch_bounds__(256) void k_pair(const unsigned short* __restrict__ AW,
                                              const unsigned short* __restrict__ Epp,
                                              const unsigned short* __restrict__ W2b,
                                              const float* __restrict__ b2,
                                              const int* __restrict__ pairs,
                                              const int* __restrict__ eds,
                                              float* __restrict__ out) {
    const int wid = blockIdx.x * 4 + (threadIdx.x >> 6);   // 0..19999
    const int lane = threadIdx.x & 63;
    const int p0 = wid * 4;
    const int b = (p0 >= NPAIRS) ? 1 : 0;                   // 40000 % 4 == 0: group shares batch
    const int n0 = lane * 8;
    const int n1 = 512 + (lane & 31) * 8;
    const bool lo = lane < 32;

    const int4 pr01 = *(const int4*)(pairs + (size_t)p0 * 2);
    const int4 pr23 = *(const int4*)(pairs + (size_t)p0 * 2 + 4);
    const int4 ed4  = *(const int4*)(eds + p0);

    const size_t base = (size_t)(b * NMENT);
    const unsigned short* a1p0 = AW + (base + pr01.x) * N_OUT;
    const unsigned short* a2p0 = AW + (base + pr01.y) * N_OUT + HIDDEN;
    const unsigned short* ep0  = Epp + (size_t)ed4.x * HIDDEN;
    const unsigned short* a1p1 = AW + (base + pr01.z) * N_OUT;
    const unsigned short* a2p1 = AW + (base + pr01.w) * N_OUT + HIDDEN;
    const unsigned short* ep1  = Epp + (size_t)ed4.y * HIDDEN;
    const unsigned short* a1p2 = AW + (base + pr23.x) * N_OUT;
    const unsigned short* a2p2 = AW + (base + pr23.y) * N_OUT + HIDDEN;
    const unsigned short* ep2  = Epp + (size_t)ed4.z * HIDDEN;
    const unsigned short* a1p3 = AW + (base + pr23.z) * N_OUT;
    const unsigned short* a2p3 = AW + (base + pr23.w) * N_OUT + HIDDEN;
    const unsigned short* ep3  = Epp + (size_t)ed4.w * HIDDEN;

    // chunk1 lane-split pointers
    const unsigned short* c01a = lo ? a1p0 : a1p1;
    const unsigned short* c01b = lo ? a2p0 : a2p1;
    const unsigned short* c01e = lo ? ep0  : ep1;
    const unsigned short* c23a = lo ? a1p2 : a1p3;
    const unsigned short* c23b = lo ? a2p2 : a2p3;
    const unsigned short* c23e = lo ? ep2  : ep3;

    // all loads 16 B, all issued before any dependent use
    uint4 w0 = *(const uint4*)(W2b + n0);
    uint4 wc = *(const uint4*)(W2b + n1);
    uint4 x1 = *(const uint4*)(a1p0 + n0), x2 = *(const uint4*)(a2p0 + n0), xe = *(const uint4*)(ep0 + n0);
    uint4 y1 = *(const uint4*)(a1p1 + n0), y2 = *(const uint4*)(a2p1 + n0), ye = *(const uint4*)(ep1 + n0);
    uint4 z1 = *(const uint4*)(a1p2 + n0), z2 = *(const uint4*)(a2p2 + n0), ze = *(const uint4*)(ep2 + n0);
    uint4 v1 = *(const uint4*)(a1p3 + n0), v2 = *(const uint4*)(a2p3 + n0), ve = *(const uint4*)(ep3 + n0);
    uint4 q1 = *(const uint4*)(c01a + n1), q2 = *(const uint4*)(c01b + n1), qe = *(const uint4*)(c01e + n1);
    uint4 s1 = *(const uint4*)(c23a + n1), s2 = *(const uint4*)(c23b + n1), se = *(const uint4*)(c23e + n1);

    float acc0 = 0.f, acc1 = 0.f, acc2 = 0.f, acc3 = 0.f;
    float cacc01 = 0.f, cacc23 = 0.f;
#define ACC2(acc, ua, ub, ue, uw)                                              \
    {                                                                          \
        float2 fa = bf2x(ua), fb = bf2x(ub), fe = bf2x(ue), fw = bf2x(uw);     \
        float h0 = fmaxf(fa.x + fb.x + fe.x, 0.f);                             \
        float h1 = fmaxf(fa.y + fb.y + fe.y, 0.f);                             \
        acc += h0 * fw.x + h1 * fw.y;                                          \
    }
    ACC2(acc0, x1.x, x2.x, xe.x, w0.x); ACC2(acc0, x1.y, x2.y, xe.y, w0.y);
    ACC2(acc0, x1.z, x2.z, xe.z, w0.z); ACC2(acc0, x1.w, x2.w, xe.w, w0.w);
    ACC2(acc1, y1.x, y2.x, ye.x, w0.x); ACC2(acc1, y1.y, y2.y, ye.y, w0.y);
    ACC2(acc1, y1.z, y2.z, ye.z, w0.z); ACC2(acc1, y1.w, y2.w, ye.w, w0.w);
    ACC2(acc2, z1.x, z2.x, ze.x, w0.x); ACC2(acc2, z1.y, z2.y, ze.y, w0.y);
    ACC2(acc2, z1.z, z2.z, ze.z, w0.z); ACC2(acc2, z1.w, z2.w, ze.w, w0.w);
    ACC2(acc3, v1.x, v2.x, ve.x, w0.x); ACC2(acc3, v1.y, v2.y, ve.y, w0.y);
    ACC2(acc3, v1.z, v2.z, ve.z, w0.z); ACC2(acc3, v1.w, v2.w, ve.w, w0.w);
    ACC2(cacc01, q1.x, q2.x, qe.x, wc.x); ACC2(cacc01, q1.y, q2.y, qe.y, wc.y);
    ACC2(cacc01, q1.z, q2.z, qe.z, wc.z); ACC2(cacc01, q1.w, q2.w, qe.w, wc.w);
    ACC2(cacc23, s1.x, s2.x, se.x, wc.x); ACC2(cacc23, s1.y, s2.y, se.y, wc.y);
    ACC2(cacc23, s1.z, s2.z, se.z, wc.z); ACC2(cacc23, s1.w, s2.w, se.w, wc.w);
#undef ACC2
    // full-wave reduce for chunk0 accs
#pragma unroll
    for (int o = 32; o > 0; o >>= 1) {
        acc0 += __shfl_xor(acc0, o, 64);
        acc1 += __shfl_xor(acc1, o, 64);
        acc2 += __shfl_xor(acc2, o, 64);
        acc3 += __shfl_xor(acc3, o, 64);
    }
    // half-wave reduce for tail accs (xor < 32 stays within each half)
#pragma unroll
    for (int o = 16; o > 0; o >>= 1) {
        cacc01 += __shfl_xor(cacc01, o, 64);
        cacc23 += __shfl_xor(cacc23, o, 64);
    }
    const float t0 = __shfl(cacc01, 0, 64);   // pair 0 tail
    const float t1 = __shfl(cacc01, 32, 64);  // pair 1 tail
    const float t2 = __shfl(cacc23, 0, 64);   // pair 2 tail
    const float t3 = __shfl(cacc23, 32, 64);  // pair 3 tail
    if (lane == 0) {
        float bias = b2[0];
        float4 o;
        o.x = acc0 + t0 + bias;
        o.y = acc1 + t1 + bias;
        o.z = acc2 + t2 + bias;
        o.w = acc3 + t3 + bias;
        *(float4*)(out + p0) = o;
    }
}

extern "C" void kernel_launch(void* const* d_in, const int* in_sizes, int n_in,
                              void* d_out, int out_size, void* d_ws, size_t ws_size,
                              hipStream_t stream) {
    const float* mention  = (const float*)d_in[0];
    const int*   pairs    = (const int*)d_in[1];
    const int*   eds      = (const int*)d_in[2];
    const float* ed_table = (const float*)d_in[3];
    const float* W1       = (const float*)d_in[4];
    const float* b1       = (const float*)d_in[5];
    const float* W2       = (const float*)d_in[6];
    const float* b2       = (const float*)d_in[7];
    float* out = (float*)d_out;

    char* ws = (char*)d_ws;
    unsigned short* Mb  = (unsigned short*)(ws);                       // 4096*768*2  = 6,291,456
    unsigned short* Wt  = (unsigned short*)(ws + 6291456);             // 1536*768*2  = 2,359,296
    unsigned short* AW  = (unsigned short*)(ws + 8650752);             // 4096*1536*2 = 12,582,912
    unsigned short* Epp = (unsigned short*)(ws + 21233664);            // 300*768*2   = 460,800
    unsigned short* W2b = (unsigned short*)(ws + 21694464);            // 768*2

    // ATTRIBUTION ROUND #2: reps=4 inflates prep and gemm into single
    // dispatches of ~4x true duration so they cross the ~44us fill floor
    // and appear in rocprof's top-5 with full counters. Idempotent.
    k_prep_all<<<dim3(NB_CONVM + NB_CONVW + NB_PREP + NB_W2), dim3(256), 0, stream>>>(
        mention, Mb, W1, Wt, ed_table, b1, Epp, W2, W2b, 4);
    k_gemm<<<dim3(M_PAD / 128, N_OUT / 64), dim3(256), 0, stream>>>(Mb, Wt, AW, 4);
    k_pair<<<dim3(TOTAL_PAIRS / 16), dim3(256), 0, stream>>>(AW, Epp, W2b, b2, pairs, eds, out);
}

// Round 7
// 120.647 us; speedup vs baseline: 1.3729x; 1.3729x over previous
//
#include <hip/hip_runtime.h>
#include <stdint.h>

#define HIDDEN 768
#define META 25
#define EDC 300
#define BB 2
#define NMENT 2000
#define NPAIRS 40000
#define M_ROWS (BB * NMENT)       // 4000
#define M_PAD 4096                // 32 * 128
#define N_OUT 1536
#define TOTAL_PAIRS (BB * NPAIRS) // 80000
#define BK 64                     // row = 128 B = full 32-bank span (enables swizzle)

typedef __bf16 bf16x8 __attribute__((ext_vector_type(8)));
typedef float f32x4 __attribute__((ext_vector_type(4)));

static __device__ __forceinline__ float bf2f(unsigned short u) {
    union { unsigned int u; float f; } v; v.u = ((unsigned int)u) << 16; return v.f;
}
static __device__ __forceinline__ float2 bf2x(unsigned int u) {
    union { unsigned int x; float f; } lo, hi;
    lo.x = u << 16; hi.x = u & 0xffff0000u;
    float2 r; r.x = lo.f; r.y = hi.f; return r;
}
static __device__ __forceinline__ unsigned short f2bf(float f) {
    union { float f; unsigned int u; } v; v.f = f;
    unsigned int u = v.u;
    unsigned int r = (u + 0x7FFFu + ((u >> 16) & 1u)) >> 16;   // RNE
    return (unsigned short)r;
}

#define GLOAD_LDS16(g, l)                                                            \
    __builtin_amdgcn_global_load_lds((const __attribute__((address_space(1))) void*)(g), \
                                     (__attribute__((address_space(3))) void*)(l), 16, 0, 0)

// ---- fused prep: convM | convW | ed prep | W2->bf16 | zero(out) ----
#define NB_CONVM 3072              // (4096*768/4)/256
#define NB_CONVW 576               // 24*24
#define NB_PREP  900               // 300*768/256
#define NB_W2    3                 // 768/256
#define NB_ZOUT  79                // 79*256*4 = 80896 >= 80000 (guarded)

__global__ __launch_bounds__(256) void k_prep_all(
        const float* __restrict__ M, unsigned short* __restrict__ Mb,
        const float* __restrict__ W1, unsigned short* __restrict__ Wt,
        const float* __restrict__ ed_table, const float* __restrict__ b1,
        unsigned short* __restrict__ Epp,
        const float* __restrict__ W2, unsigned short* __restrict__ W2b,
        float* __restrict__ out) {
    const int blk = blockIdx.x;
    const int t = threadIdx.x;
    if (blk < NB_CONVM) {
        int idx = (blk * 256 + t) * 4;
        int row = idx / HIDDEN;
        ushort4 o;
        if (row < M_ROWS) {
            const float4 v = *(const float4*)(M + idx);
            o.x = f2bf(v.x); o.y = f2bf(v.y); o.z = f2bf(v.z); o.w = f2bf(v.w);
        } else {
            o.x = 0; o.y = 0; o.z = 0; o.w = 0;
        }
        *(ushort4*)(Mb + idx) = o;
    } else if (blk < NB_CONVM + NB_CONVW) {
        __shared__ float tile[32][68];
        int id = blk - NB_CONVM;
        int nt = id % 24, kt = id / 24;
        int n0 = nt * 64, k0 = kt * 32;
        int tk = t >> 4, tn = (t & 15) * 4;
        int srcRowOff = (n0 < HIDDEN) ? 0 : HIDDEN;
        int srcColBase = (n0 < HIDDEN) ? n0 : (n0 - HIDDEN);
        {
            const float4 v0 = *(const float4*)(W1 + (size_t)(k0 + tk + srcRowOff) * HIDDEN + srcColBase + tn);
            tile[tk][tn] = v0.x; tile[tk][tn + 1] = v0.y; tile[tk][tn + 2] = v0.z; tile[tk][tn + 3] = v0.w;
            const float4 v1 = *(const float4*)(W1 + (size_t)(k0 + tk + 16 + srcRowOff) * HIDDEN + srcColBase + tn);
            tile[tk + 16][tn] = v1.x; tile[tk + 16][tn + 1] = v1.y; tile[tk + 16][tn + 2] = v1.z; tile[tk + 16][tn + 3] = v1.w;
        }
        __syncthreads();
        int wn = t >> 2, wk = (t & 3) * 8;
        unsigned int p0 = (unsigned int)f2bf(tile[wk + 0][wn]) | ((unsigned int)f2bf(tile[wk + 1][wn]) << 16);
        unsigned int p1 = (unsigned int)f2bf(tile[wk + 2][wn]) | ((unsigned int)f2bf(tile[wk + 3][wn]) << 16);
        unsigned int p2 = (unsigned int)f2bf(tile[wk + 4][wn]) | ((unsigned int)f2bf(tile[wk + 5][wn]) << 16);
        unsigned int p3 = (unsigned int)f2bf(tile[wk + 6][wn]) | ((unsigned int)f2bf(tile[wk + 7][wn]) << 16);
        uint4 pk; pk.x = p0; pk.y = p1; pk.z = p2; pk.w = p3;
        *(uint4*)(Wt + (size_t)(n0 + wn) * HIDDEN + k0 + wk) = pk;
    } else if (blk < NB_CONVM + NB_CONVW + NB_PREP) {
        int id = (blk - NB_CONVM - NB_CONVW) * 256 + t;
        int e = id / HIDDEN, n = id - e * HIDDEN;
        float acc = b1[n];
#pragma unroll
        for (int k = 0; k < META; k++)
            acc += ed_table[e * META + k] * W1[(size_t)(2 * HIDDEN + k) * HIDDEN + n];
        Epp[id] = f2bf(acc);
    } else if (blk < NB_CONVM + NB_CONVW + NB_PREP + NB_W2) {
        int id = (blk - NB_CONVM - NB_CONVW - NB_PREP) * 256 + t;
        if (id < HIDDEN) W2b[id] = f2bf(W2[id]);
    } else {
        // zero the output accumulator (k_pair atomically accumulates 2 H-chunks)
        int i4 = (blk - (NB_CONVM + NB_CONVW + NB_PREP + NB_W2)) * 256 + t;
        if (i4 * 4 < TOTAL_PAIRS) {
            float4 z; z.x = 0.f; z.y = 0.f; z.z = 0.f; z.w = 0.f;
            *(float4*)(out + i4 * 4) = z;
        }
    }
}

// ---- AW[4096][1536] = Mb @ Wt^T ---- (baseline, 695 TF measured R5)
__global__ __launch_bounds__(256) void k_gemm(const unsigned short* __restrict__ Mb,
                                              const unsigned short* __restrict__ Wt,
                                              unsigned short* __restrict__ AW) {
    __shared__ unsigned short As[128 * BK];   // 16 KB
    __shared__ unsigned short Bs[64 * BK];    // 8 KB
    const int m0 = blockIdx.x * 128;
    const int n0 = blockIdx.y * 64;
    const int t = threadIdx.x, w = t >> 6, lane = t & 63;
    const int wm = (w & 1) * 64, wn = (w >> 1) * 32;
    const int q = lane >> 4, r = lane & 15;
    const int lrow = lane >> 3;
    const int lcol = ((((lane & 7) - lrow) & 7)) * 8;      // shorts
    const unsigned short* gA = Mb + (size_t)(m0 + w * 32 + lrow) * HIDDEN + lcol;
    const unsigned short* gB = Wt + (size_t)(n0 + w * 16 + lrow) * HIDDEN + lcol;
    unsigned short* lA = As + (w * 32) * BK;               // wave-uniform LDS base
    unsigned short* lB = Bs + (w * 16) * BK;
    f32x4 acc[4][2] = {};
    for (int k0 = 0; k0 < HIDDEN; k0 += BK) {
        GLOAD_LDS16(gA + k0, lA);
        GLOAD_LDS16(gA + k0 + 8 * HIDDEN,  lA + 8 * BK);
        GLOAD_LDS16(gA + k0 + 16 * HIDDEN, lA + 16 * BK);
        GLOAD_LDS16(gA + k0 + 24 * HIDDEN, lA + 24 * BK);
        GLOAD_LDS16(gB + k0, lB);
        GLOAD_LDS16(gB + k0 + 8 * HIDDEN,  lB + 8 * BK);
        __syncthreads();
        bf16x8 af[4][2], bfr[2][2];
        const int rs = r & 7;
#pragma unroll
        for (int i = 0; i < 4; i++)
#pragma unroll
            for (int s = 0; s < 2; s++)
                af[i][s] = *(const bf16x8*)&As[(wm + i * 16 + r) * BK + 8 * ((q + 4 * s + rs) & 7)];
#pragma unroll
        for (int j = 0; j < 2; j++)
#pragma unroll
            for (int s = 0; s < 2; s++)
                bfr[j][s] = *(const bf16x8*)&Bs[(wn + j * 16 + r) * BK + 8 * ((q + 4 * s + rs) & 7)];
#pragma unroll
        for (int i = 0; i < 4; i++)
#pragma unroll
            for (int j = 0; j < 2; j++) {
                acc[i][j] = __builtin_amdgcn_mfma_f32_16x16x32_bf16(af[i][0], bfr[j][0], acc[i][j], 0, 0, 0);
                acc[i][j] = __builtin_amdgcn_mfma_f32_16x16x32_bf16(af[i][1], bfr[j][1], acc[i][j], 0, 0, 0);
            }
        __syncthreads();
    }
    const int colb = n0 + wn + (lane & 15);
    const int rowb = m0 + wm + (lane >> 4) * 4;
#pragma unroll
    for (int i = 0; i < 4; i++)
#pragma unroll
        for (int j = 0; j < 2; j++) {
            unsigned short* dst = AW + (size_t)(rowb + i * 16) * N_OUT + colb + j * 16;
#pragma unroll
            for (int reg = 0; reg < 4; reg++)
                dst[(size_t)reg * N_OUT] = f2bf(acc[i][j][reg]);
        }
}

// ---- pair phase: 2 H-chunks x 384 elems, XCD-pinned, FAT waves ----
// R3 lesson: chunking must keep per-wave amortization. Here each wave still
// owns 4 pairs (baseline's setup/reduction amortization), but only one
// 384-elem H-chunk. slot = blockIdx&3 = (batch<<1)|chunk; with blockIdx&7
// XCD round-robin, XCDs {s, s+4} serve slot s -> per-XCD footprint =
// 1.5 (A1 half) + 1.5 (A2 half) + 0.23 (Epp half) = 3.2 MB < 4 MB L2.
// Per lane: 6 elems = 12 B uint3; 64 lanes x 12 B = 768 B contiguous per
// stream (fully packed 128B lines). Partials combined with 2 atomicAdds per
// pair into pre-zeroed out ((0+x)+y == (0+y)+x in IEEE -> deterministic).
__global__ __launch_bounds__(256) void k_pair(const unsigned short* __restrict__ AW,
                                              const unsigned short* __restrict__ Epp,
                                              const unsigned short* __restrict__ W2b,
                                              const float* __restrict__ b2,
                                              const int* __restrict__ pairs,
                                              const int* __restrict__ eds,
                                              float* __restrict__ out) {
    const int bi = blockIdx.x;                 // [0, 10000)
    const int slot = bi & 3;
    const int batch = slot >> 1;               // 0..1
    const int c     = slot & 1;                // H-chunk 0..1
    const int wv = threadIdx.x >> 6;
    const int lane = threadIdx.x & 63;
    const int wid = (bi >> 2) * 4 + wv;        // [0, 10000) within slot
    const int p0 = batch * NPAIRS + wid * 4;   // 4 pairs, all same batch
    const size_t base = (size_t)batch * NMENT;

    const int4 pr01 = *(const int4*)(pairs + (size_t)p0 * 2);
    const int4 pr23 = *(const int4*)(pairs + (size_t)p0 * 2 + 4);
    const int4 ed4  = *(const int4*)(eds + p0);

    const int e0 = c * 384 + lane * 6;         // element offset in [0,768)
    const unsigned short* a1p0 = AW + (base + pr01.x) * N_OUT + e0;
    const unsigned short* a2p0 = AW + (base + pr01.y) * N_OUT + HIDDEN + e0;
    const unsigned short* ep0  = Epp + (size_t)ed4.x * HIDDEN + e0;
    const unsigned short* a1p1 = AW + (base + pr01.z) * N_OUT + e0;
    const unsigned short* a2p1 = AW + (base + pr01.w) * N_OUT + HIDDEN + e0;
    const unsigned short* ep1  = Epp + (size_t)ed4.y * HIDDEN + e0;
    const unsigned short* a1p2 = AW + (base + pr23.x) * N_OUT + e0;
    const unsigned short* a2p2 = AW + (base + pr23.y) * N_OUT + HIDDEN + e0;
    const unsigned short* ep2  = Epp + (size_t)ed4.z * HIDDEN + e0;
    const unsigned short* a1p3 = AW + (base + pr23.z) * N_OUT + e0;
    const unsigned short* a2p3 = AW + (base + pr23.w) * N_OUT + HIDDEN + e0;
    const unsigned short* ep3  = Epp + (size_t)ed4.w * HIDDEN + e0;

    // 13 x 12 B loads, all issued before any dependent use
    const uint3 wv3 = *(const uint3*)(W2b + e0);
    const uint3 x1 = *(const uint3*)a1p0, x2 = *(const uint3*)a2p0, xe = *(const uint3*)ep0;
    const uint3 y1 = *(const uint3*)a1p1, y2 = *(const uint3*)a2p1, ye = *(const uint3*)ep1;
    const uint3 z1 = *(const uint3*)a1p2, z2 = *(const uint3*)a2p2, ze = *(const uint3*)ep2;
    const uint3 v1 = *(const uint3*)a1p3, v2 = *(const uint3*)a2p3, ve = *(const uint3*)ep3;

    float acc0 = 0.f, acc1 = 0.f, acc2 = 0.f, acc3 = 0.f;
#define ACC2(acc, ua, ub, ue, uw)                                              \
    {                                                                          \
        float2 fa = bf2x(ua), fb = bf2x(ub), fe = bf2x(ue), fw = bf2x(uw);     \
        float h0 = fmaxf(fa.x + fb.x + fe.x, 0.f);                             \
        float h1 = fmaxf(fa.y + fb.y + fe.y, 0.f);                             \
        acc += h0 * fw.x + h1 * fw.y;                                          \
    }
    ACC2(acc0, x1.x, x2.x, xe.x, wv3.x); ACC2(acc0, x1.y, x2.y, xe.y, wv3.y);
    ACC2(acc0, x1.z, x2.z, xe.z, wv3.z);
    ACC2(acc1, y1.x, y2.x, ye.x, wv3.x); ACC2(acc1, y1.y, y2.y, ye.y, wv3.y);
    ACC2(acc1, y1.z, y2.z, ye.z, wv3.z);
    ACC2(acc2, z1.x, z2.x, ze.x, wv3.x); ACC2(acc2, z1.y, z2.y, ze.y, wv3.y);
    ACC2(acc2, z1.z, z2.z, ze.z, wv3.z);
    ACC2(acc3, v1.x, v2.x, ve.x, wv3.x); ACC2(acc3, v1.y, v2.y, ve.y, wv3.y);
    ACC2(acc3, v1.z, v2.z, ve.z, wv3.z);
#undef ACC2

    // full-wave butterfly for all 4 pair-partials
#pragma unroll
    for (int o = 32; o > 0; o >>= 1) {
        acc0 += __shfl_xor(acc0, o, 64);
        acc1 += __shfl_xor(acc1, o, 64);
        acc2 += __shfl_xor(acc2, o, 64);
        acc3 += __shfl_xor(acc3, o, 64);
    }

    if (lane == 0) {
        const float bias = (c == 0) ? b2[0] : 0.f;   // bias added once (chunk 0)
        atomicAdd(out + p0 + 0, acc0 + bias);
        atomicAdd(out + p0 + 1, acc1 + bias);
        atomicAdd(out + p0 + 2, acc2 + bias);
        atomicAdd(out + p0 + 3, acc3 + bias);
    }
}

extern "C" void kernel_launch(void* const* d_in, const int* in_sizes, int n_in,
                              void* d_out, int out_size, void* d_ws, size_t ws_size,
                              hipStream_t stream) {
    const float* mention  = (const float*)d_in[0];
    const int*   pairs    = (const int*)d_in[1];
    const int*   eds      = (const int*)d_in[2];
    const float* ed_table = (const float*)d_in[3];
    const float* W1       = (const float*)d_in[4];
    const float* b1       = (const float*)d_in[5];
    const float* W2       = (const float*)d_in[6];
    const float* b2       = (const float*)d_in[7];
    float* out = (float*)d_out;

    char* ws = (char*)d_ws;
    unsigned short* Mb  = (unsigned short*)(ws);                       // 4096*768*2  = 6,291,456
    unsigned short* Wt  = (unsigned short*)(ws + 6291456);             // 1536*768*2  = 2,359,296
    unsigned short* AW  = (unsigned short*)(ws + 8650752);             // 4096*1536*2 = 12,582,912
    unsigned short* Epp = (unsigned short*)(ws + 21233664);            // 300*768*2   = 460,800
    unsigned short* W2b = (unsigned short*)(ws + 21694464);            // 768*2

    k_prep_all<<<dim3(NB_CONVM + NB_CONVW + NB_PREP + NB_W2 + NB_ZOUT), dim3(256), 0, stream>>>(
        mention, Mb, W1, Wt, ed_table, b1, Epp, W2, W2b, out);
    k_gemm<<<dim3(M_PAD / 128, N_OUT / 64), dim3(256), 0, stream>>>(Mb, Wt, AW);
    k_pair<<<dim3(10000), dim3(256), 0, stream>>>(AW, Epp, W2b, b2, pairs, eds, out);
}